// Round 2
// baseline (923.349 us; speedup 1.0000x reference)
//
#include <hip/hip_runtime.h>
#include <math.h>

// ---------------------------------------------------------------------------
// CapsuleNet forward (round 20): prim_gemm widened to BN=256 (full N):
// 512 threads / 8 waves (2m x 4n), BM=128, BK=32, split-K x16 (kb-level,
// kt%8 -> XCD-pinned B slice). A-tile now gathered ONCE per (mt,kt) (was 2x
// for nt=0/1), LDS 48KB -> 3 blocks/CU (24 waves, was 12), grid 2304 =
// exactly 3.0 resident rounds. Staging unchanged from round 19:
// global_load_lds width=16 into linear double-buffered LDS, 1 barrier/K-step.
// Everything else identical to round-19:
//  - conv1: MFMA implicit im2col                     [round 13]
//  - priors_k/routing2_k two-phase + it0 shortcut    [rounds 6/12/14]
//  - dec1 fused argmax+sparse GEMM, prep_k fused     [round 12]
// ---------------------------------------------------------------------------

typedef _Float16 h16;
typedef h16 frag8 __attribute__((ext_vector_type(8)));    // 8 halves = 16 B
typedef float f32x4 __attribute__((ext_vector_type(4)));

// workspace layout (BYTE offsets).
#define OFFB_HHI   0L             // 52428800 halves = 104857600 B
#define OFFB_WTHI  209715200L     // 5308416 halves = 10616832 B
#define OFFB_WT1   230948864L     // w1t: 24576 halves = 49152 B
#define OFFB_C     231031808L     // 4718592 floats -> end 249906176
#define WS_BYTES   249906176L
// aliased into dead h region after prim_gemm:
#define OFFB_PRI   0L             // 94371840 halves = 188743680 B (priors fp16)
#define OFFB_UT    188743680L     // 4718592 halves = 9437184 B -> OK
// aliased into dead wt region after prim_gemm:
#define OFFB_V     209715200L     // 81920 floats
#define OFFB_D1    210370560L     // 262144 floats
#define OFFB_D2    211419136L     // 524288 floats -> 213516288 OK

// async global->LDS, 16 B per lane. LDS dest must be lane-linear:
// lane i of a wave writes base + i*16 B.
#define GLL16(gp, lp)                                                        \
    __builtin_amdgcn_global_load_lds(                                        \
        (const __attribute__((address_space(1))) void*)(gp),                 \
        (__attribute__((address_space(3))) void*)(lp), 16, 0, 0)

// --------------------------------------------------------------------------
// prep: blocks 0..95: w1t[oc][96] fp16 (k-padded); 96..351: prim B^T fp16;
// 352..18783: zero C.
__global__ __launch_bounds__(256) void prep_k(const float* __restrict__ w1,
                                              const float* __restrict__ pw,
                                              h16* __restrict__ w1t,
                                              h16* __restrict__ whi,
                                              float* __restrict__ C) {
    __shared__ float s[2592];
    int bx = blockIdx.x, tid = threadIdx.x;
    if (bx < 96) {
        int k = bx, oc = tid;
        w1t[(long)oc * 96 + k] = (k < 81) ? (h16)w1[oc * 81 + k] : (h16)0.f;
    } else if (bx < 352) {
        int oc = bx - 96;
        long src0 = (long)oc * 20736, dst0 = src0;
        for (int ch = 0; ch < 8; ++ch) {
            int ic0 = ch * 32;
            __syncthreads();
            for (int e = tid; e < 2592; e += 256) s[e] = pw[src0 + ic0 * 81 + e];
            __syncthreads();
            for (int e = tid; e < 2592; e += 256) {
                int tap = e >> 5, icf = e & 31;
                whi[dst0 + tap * 256 + ic0 + icf] = (h16)s[icf * 81 + tap];
            }
        }
    } else {
        long i = (long)(bx - 352) * 256 + tid;   // 18432 blocks * 256 = 4718592
        C[i] = 0.f;
    }
}

// --------------------------------------------------------------------------
// conv1 as MFMA implicit-im2col GEMM. Grid 3200: nt = bx&1, mt = bx>>1.
#define CLDK 104
__global__ __launch_bounds__(256, 2) void conv1_mfma(const float* __restrict__ x,
                                                     const h16* __restrict__ w1t,
                                                     const float* __restrict__ bias,
                                                     h16* __restrict__ hhi) {
    __shared__ h16 Al[128 * CLDK];
    __shared__ h16 Bw[128 * CLDK];
    int tid = threadIdx.x;
    int bx = blockIdx.x;
    int nt = bx & 1, mt = bx >> 1;
    int n0 = nt * 128;

    for (int e = tid; e < 128 * 96; e += 256) {
        int oc = e / 96, k = e - (e / 96) * 96;
        Bw[oc * CLDK + k] = w1t[(long)(n0 + oc) * 96 + k];
    }
    for (int e = tid; e < 128 * 96; e += 256) {
        int ml = e / 96, k = e - (e / 96) * 96;
        int m = mt * 128 + ml;
        int b = m / 400, pix = m - b * 400;
        int oy = pix / 20, ox = pix - oy * 20;
        float v = 0.f;
        if (k < 81) {
            int ky = k / 9, kx = k - ky * 9;
            v = x[(long)b * 784 + (oy + ky) * 28 + (ox + kx)];
        }
        Al[ml * CLDK + k] = (h16)v;
    }
    __syncthreads();

    int wave = tid >> 6;
    int wm = wave >> 1, wn = wave & 1;
    int lane = tid & 63;
    int lm = lane & 15, quad = lane >> 4;

    f32x4 acc[4][4];
#pragma unroll
    for (int i = 0; i < 4; ++i)
#pragma unroll
        for (int j = 0; j < 4; ++j) acc[i][j] = (f32x4){0.f, 0.f, 0.f, 0.f};

#pragma unroll
    for (int ks = 0; ks < 3; ++ks) {
        int kc = ks * 32 + quad * 8;
        frag8 af[4], bf[4];
#pragma unroll
        for (int mi = 0; mi < 4; ++mi)
            af[mi] = *(const frag8*)&Al[(wm * 64 + mi * 16 + lm) * CLDK + kc];
#pragma unroll
        for (int ni = 0; ni < 4; ++ni)
            bf[ni] = *(const frag8*)&Bw[(wn * 64 + ni * 16 + lm) * CLDK + kc];
#pragma unroll
        for (int mi = 0; mi < 4; ++mi)
#pragma unroll
            for (int ni = 0; ni < 4; ++ni)
                acc[mi][ni] = __builtin_amdgcn_mfma_f32_16x16x32_f16(
                    af[mi], bf[ni], acc[mi][ni], 0, 0, 0);
    }

#pragma unroll
    for (int ni = 0; ni < 4; ++ni) {
        int oc = n0 + wn * 64 + ni * 16 + lm;
        float bv = bias[oc];
#pragma unroll
        for (int mi = 0; mi < 4; ++mi) {
            int m = mt * 128 + wm * 64 + mi * 16 + quad * 4;
#pragma unroll
            for (int r = 0; r < 4; ++r)
                hhi[(long)(m + r) * 256 + oc] = (h16)fmaxf(acc[mi][ni][r] + bv, 0.f);
        }
    }
}

// --------------------------------------------------------------------------
// prim conv MFMA GEMM (round 20): BM=128 BN=256 BK=32, 512 threads / 8 waves
// (wave tile 64x64, wave grid 2m x 4n). split-K x16 at kb granularity:
// kts 0..7 own 41 kb-steps, kts 8..15 own 40 (648 total); kt%8 = bx%8 ->
// XCD-pinned B slice (~1.3 MB/XCD, L2-resident). Staging via global_load_lds
// dwordx4 into double-buffered LINEAR LDS (A: [128][32], B: [256][32]);
// one barrier per K-step. Atomic accumulate into zeroed C.
// LDS 48 KB -> 3 blocks/CU resident; grid 2304 = 3.0 exact rounds.
#define PLDA (128 * 32)
#define PLDB (256 * 32)
__global__ __launch_bounds__(512, 4) void prim_gemm_mfma(
        const h16* __restrict__ Ahi, const h16* __restrict__ Bhi,
        float* __restrict__ C) {
    __shared__ __align__(16) h16 As[2][PLDA];
    __shared__ __align__(16) h16 Bs[2][PLDB];
    int tid = threadIdx.x;
    int bx = blockIdx.x;                  // 2304 blocks
    int kt = bx & 15;
    int mt = bx >> 4;                     // 0..143
    int kb0 = kt * 40 + (kt < 8 ? kt : 8);
    int nkb = 40 + (kt < 8 ? 1 : 0);

    int wave = tid >> 6;
    int wm = wave >> 2, wn = wave & 3;    // 2 x 4 wave grid
    int lane = tid & 63;
    int lm = lane & 15, quad = lane >> 4;

    // staging geometry: thread t covers LDS halves [t*8, t*8+8):
    // A: row r0 = t>>2 (0..127), col c0 = (t&3)*8  (8 KB = one GLL16 round)
    // B: rows r0 and r0+128 (16 KB = two GLL16 rounds)
    int c0 = (tid & 3) * 8;
    int r0 = tid >> 2;
    long abase, bbase0, bbase1;
    {
        int m = mt * 128 + r0;
        int b = m / 36, pos = m - b * 36;
        int oy = pos / 6, ox = pos - oy * 6;
        abase = ((long)(b * 20 + 2 * oy) * 20 + 2 * ox) * 256 + c0;
        bbase0 = (long)r0 * 20736 + c0;
        bbase1 = (long)(r0 + 128) * 20736 + c0;
    }
    h16* la = &As[0][tid * 8];
    h16* lb = &Bs[0][tid * 8];

    auto stage = [&](int buf, int kb) {
        // wave-uniform K-step decode (lands in SGPRs)
        int tap = kb >> 3;
        int ic0 = (kb & 7) << 5;
        int ky = tap / 9, kx = tap - ky * 9;
        long aoff = (long)(ky * 20 + kx) * 256 + ic0;
        long boff = (long)kb * 32;
        GLL16(Ahi + abase + aoff, la + (long)buf * PLDA);
        GLL16(Bhi + bbase0 + boff, lb + (long)buf * PLDB);
        GLL16(Bhi + bbase1 + boff, lb + (long)buf * PLDB + 4096);
    };

    f32x4 acc[4][4];
#pragma unroll
    for (int i = 0; i < 4; ++i)
#pragma unroll
        for (int j = 0; j < 4; ++j) acc[i][j] = (f32x4){0.f, 0.f, 0.f, 0.f};

    stage(0, kb0);
    for (int it = 0; it < nkb; ++it) {
        int cur = it & 1;
        // one barrier per K-step: drains vmcnt (buf[cur] staged) and lgkm
        // (prev iter's ds_reads of buf[cur^1] done before we overwrite it).
        __syncthreads();
        if (it + 1 < nkb) stage(cur ^ 1, kb0 + it + 1);

        frag8 ah[4], bh[4];
#pragma unroll
        for (int mi = 0; mi < 4; ++mi) {
            int row = wm * 64 + mi * 16 + lm;
            ah[mi] = *(const frag8*)&As[cur][row * 32 + quad * 8];
        }
#pragma unroll
        for (int ni = 0; ni < 4; ++ni) {
            int col = wn * 64 + ni * 16 + lm;
            bh[ni] = *(const frag8*)&Bs[cur][col * 32 + quad * 8];
        }
#pragma unroll
        for (int mi = 0; mi < 4; ++mi)
#pragma unroll
            for (int ni = 0; ni < 4; ++ni)
                acc[mi][ni] = __builtin_amdgcn_mfma_f32_16x16x32_f16(
                    ah[mi], bh[ni], acc[mi][ni], 0, 0, 0);
    }

#pragma unroll
    for (int ni = 0; ni < 4; ++ni) {
        int n = wn * 64 + ni * 16 + lm;
#pragma unroll
        for (int mi = 0; mi < 4; ++mi) {
            int m = mt * 128 + wm * 64 + mi * 16 + quad * 4;
#pragma unroll
            for (int r = 0; r < 4; ++r)
                atomicAdd(&C[(long)(m + r) * 256 + n], acc[mi][ni][r]);
        }
    }
}

// --------------------------------------------------------------------------
// squash: C[(b*36+pos)][256] (+bias) -> ut[n][b][8] fp16, n = ci*36+pos.
__global__ void squash_k(const float* __restrict__ C,
                         const float* __restrict__ bias,
                         h16* __restrict__ ut) {
    int t = blockIdx.x * 256 + threadIdx.x;          // 589824 exact
    int row = t >> 5;                                 // (b*36+pos)
    int ci = t & 31;
    int b = row / 36, pos = row - b * 36;
    const float* src = C + (long)row * 256 + ci;
    float v[8]; float sn = 0.f;
#pragma unroll
    for (int i = 0; i < 8; ++i) {
        v[i] = src[i * 32] + bias[ci + i * 32];
        sn = fmaf(v[i], v[i], sn);
    }
    float scale = (sn / (1.f + sn)) / sqrtf(sn);
    frag8 o;
#pragma unroll
    for (int i = 0; i < 8; ++i) o[i] = (h16)(v[i] * scale);
    *(frag8*)(ut + ((long)(ci * 36 + pos) * 512 + b) * 8) = o;
}

// --------------------------------------------------------------------------
// Phase A: priors[c,b,n,:16] = ut[n,b,:8] @ rw[c,n,:8,:16], fp16 out.
__global__ __launch_bounds__(256) void priors_k(const h16* __restrict__ ut,
                                                const float* __restrict__ rw,
                                                h16* __restrict__ priors) {
    int bid = blockIdx.x;                 // 1440 = 10 c * 144 n-groups
    int c = bid / 144, ng = bid - c * 144;
    int n0 = ng * 8;
    __shared__ float w[8][132];
    int tid = threadIdx.x;
    for (int e = tid; e < 1024; e += 256)
        w[e >> 7][e & 127] = rw[((long)c * 1152 + n0 + (e >> 7)) * 128 + (e & 127)];
    __syncthreads();
    int nl = tid & 7, bl = tid >> 3;      // bl 0..31
    int n = n0 + nl;
    for (int ch = 0; ch < 16; ++ch) {
        int b = ch * 32 + bl;
        frag8 uv = *(const frag8*)(ut + ((long)n * 512 + b) * 8);
        float uu[8];
#pragma unroll
        for (int i = 0; i < 8; ++i) uu[i] = (float)uv[i];
        float o[16];
#pragma unroll
        for (int j = 0; j < 16; ++j) o[j] = 0.f;
#pragma unroll
        for (int i = 0; i < 8; ++i)
#pragma unroll
            for (int j = 0; j < 16; ++j)
                o[j] = fmaf(uu[i], w[nl][i * 16 + j], o[j]);
        frag8 p0, p1;
#pragma unroll
        for (int j = 0; j < 8; ++j) { p0[j] = (h16)o[j]; p1[j] = (h16)o[j + 8]; }
        h16* dst = priors + ((long)(c * 512 + b) * 1152 + n) * 16;
        *(frag8*)dst = p0;
        *(frag8*)(dst + 8) = p1;
    }
}

// --------------------------------------------------------------------------
// Phase B: 3-iter routing. Block per (c,b). Iteration 0 uses the exact
// uniform-softmax shortcut (initial logits identically 0 -> probs = 1/1152).
__global__ __launch_bounds__(384) void routing2_k(const h16* __restrict__ priors,
                                                  float* __restrict__ vbuf) {
    int c = blockIdx.x >> 9;
    int b = blockIdx.x & 511;
    int tid = threadIdx.x;
    int wid = tid >> 6;
    int lane = tid & 63;
    __shared__ float wred[6][20];

    float pr[3][16];
#pragma unroll
    for (int r = 0; r < 3; ++r) {
        int n = tid + r * 384;
        const h16* pp = priors + ((long)(c * 512 + b) * 1152 + n) * 16;
        frag8 p0 = *(const frag8*)pp;
        frag8 p1 = *(const frag8*)(pp + 8);
#pragma unroll
        for (int o = 0; o < 8; ++o) { pr[r][o] = (float)p0[o]; pr[r][o + 8] = (float)p1[o]; }
    }

    float l0 = 0.f, l1 = 0.f, l2 = 0.f;
    float vout[16];

    // ---- iteration 0: probs uniform = 1/1152 ----
    {
        float red[16];
#pragma unroll
        for (int o = 0; o < 16; ++o) red[o] = pr[0][o] + pr[1][o] + pr[2][o];
#pragma unroll
        for (int o = 0; o < 16; ++o) {
#pragma unroll
            for (int m = 32; m >= 1; m >>= 1) red[o] += __shfl_xor(red[o], m);
        }
        if (lane == 0) {
#pragma unroll
            for (int o = 0; o < 16; ++o) wred[wid][o] = red[o];
        }
        __syncthreads();
        float inv = 1.f / 1152.f;
        float sn = 0.f;
        float sv[16];
#pragma unroll
        for (int o = 0; o < 16; ++o) {
            float tacc = wred[0][o];
#pragma unroll
            for (int w = 1; w < 6; ++w) tacc += wred[w][o];
            sv[o] = tacc * inv;
            sn = fmaf(sv[o], sv[o], sn);
        }
        float scale = (sn / (1.f + sn)) / sqrtf(sn);
#pragma unroll
        for (int o = 0; o < 16; ++o) vout[o] = sv[o] * scale;
        float d0 = 0.f, d1 = 0.f, d2 = 0.f;
#pragma unroll
        for (int o = 0; o < 16; ++o) {
            d0 = fmaf(pr[0][o], vout[o], d0);
            d1 = fmaf(pr[1][o], vout[o], d1);
            d2 = fmaf(pr[2][o], vout[o], d2);
        }
        l0 = d0; l1 = d1; l2 = d2;
        __syncthreads();                 // wred reused next iteration
    }

    // ---- iterations 1,2: full softmax path ----
    for (int it = 1; it < 3; ++it) {
        float lm = fmaxf(fmaxf(l0, l1), l2);
#pragma unroll
        for (int m = 32; m >= 1; m >>= 1) lm = fmaxf(lm, __shfl_xor(lm, m));
        if (lane == 0) wred[wid][17] = lm;
        __syncthreads();
        float maxv = wred[0][17];
#pragma unroll
        for (int w = 1; w < 6; ++w) maxv = fmaxf(maxv, wred[w][17]);

        float e0 = expf(l0 - maxv), e1 = expf(l1 - maxv), e2 = expf(l2 - maxv);
        float red[17];
#pragma unroll
        for (int o = 0; o < 16; ++o)
            red[o] = fmaf(e0, pr[0][o], fmaf(e1, pr[1][o], e2 * pr[2][o]));
        red[16] = e0 + e1 + e2;
#pragma unroll
        for (int o = 0; o < 17; ++o) {
#pragma unroll
            for (int m = 32; m >= 1; m >>= 1) red[o] += __shfl_xor(red[o], m);
        }
        __syncthreads();
        if (lane == 0) {
#pragma unroll
            for (int o = 0; o < 17; ++o) wred[wid][o] = red[o];
        }
        __syncthreads();
        float sv[17];
#pragma unroll
        for (int o = 0; o < 17; ++o) {
            float tacc = wred[0][o];
#pragma unroll
            for (int w = 1; w < 6; ++w) tacc += wred[w][o];
            sv[o] = tacc;
        }
        float inv = 1.f / sv[16];
        float sn = 0.f;
#pragma unroll
        for (int o = 0; o < 16; ++o) { float s = sv[o] * inv; sn = fmaf(s, s, sn); }
        float scale = (sn / (1.f + sn)) / sqrtf(sn);
#pragma unroll
        for (int o = 0; o < 16; ++o) vout[o] = sv[o] * inv * scale;

        if (it < 2) {
            float d0 = 0.f, d1 = 0.f, d2 = 0.f;
#pragma unroll
            for (int o = 0; o < 16; ++o) {
                d0 = fmaf(pr[0][o], vout[o], d0);
                d1 = fmaf(pr[1][o], vout[o], d1);
                d2 = fmaf(pr[2][o], vout[o], d2);
            }
            l0 += d0; l1 += d1; l2 += d2;
        }
    }
    if (tid < 16) vbuf[(b * 10 + c) * 16 + tid] = vout[tid];
}

// --------------------------------------------------------------------------
// dec1: fused classes/argmax/y_pred + sparse masked GEMM (K=16 of 160).
__global__ __launch_bounds__(512) void dec1_k(const float* __restrict__ vbuf,
                                              const float* __restrict__ dw1,
                                              const float* __restrict__ db1,
                                              float* __restrict__ out,
                                              float* __restrict__ d1) {
    __shared__ float sv[160];
    __shared__ float scls[10];
    __shared__ int sbest;
    int b = blockIdx.x, tid = threadIdx.x;
    if (tid < 160) sv[tid] = vbuf[b * 160 + tid];
    __syncthreads();
    if (tid < 10) {
        float sn = 0.f;
#pragma unroll
        for (int o = 0; o < 16; ++o) { float v = sv[tid * 16 + o]; sn = fmaf(v, v, sn); }
        scls[tid] = sqrtf(sn);
    }
    __syncthreads();
    if (tid == 0) {
        int best = 0; float bv = scls[0];
#pragma unroll
        for (int cc = 1; cc < 10; ++cc) if (scls[cc] > bv) { bv = scls[cc]; best = cc; }
        sbest = best;
    }
    __syncthreads();
    int best = sbest;
    if (tid < 10) {
        out[b * 10 + tid] = (tid == best) ? 1.f : 0.f;          // y_pred
        out[406528 + b * 10 + tid] = scls[tid];                 // classes
    }
    float acc = db1[tid];
    const float* wrow = dw1 + (long)best * 16 * 512;
#pragma unroll
    for (int i = 0; i < 16; ++i)
        acc = fmaf(sv[best * 16 + i], wrow[i * 512 + tid], acc);
    d1[(long)b * 512 + tid] = fmaxf(acc, 0.f);
}

// --------------------------------------------------------------------------
template <int ACT>
__global__ __launch_bounds__(256) void dec_gemm(const float* __restrict__ A,
                                                const float* __restrict__ Bw,
                                                const float* __restrict__ bias,
                                                float* __restrict__ C,
                                                int M, int N, int K) {
    __shared__ float As[16][68];
    __shared__ float Bs[16][68];
    int ntiles = (N + 63) >> 6;
    int mt = blockIdx.x / ntiles, nt = blockIdx.x - mt * ntiles;
    int m0 = mt * 64, n0 = nt * 64;
    int tid = threadIdx.x;
    int tx = tid & 15, ty = tid >> 4;
    int am = tid >> 2, ak = (tid & 3) * 4;
    int bk = tid >> 4, bn = (tid & 15) * 4;
    float acc[4][4];
#pragma unroll
    for (int i = 0; i < 4; ++i)
#pragma unroll
        for (int j = 0; j < 4; ++j) acc[i][j] = 0.f;

    for (int k0 = 0; k0 < K; k0 += 16) {
        float4 av = *(const float4*)(A + (m0 + am) * K + k0 + ak);
        float4 bv = make_float4(0.f, 0.f, 0.f, 0.f);
        if (n0 + bn < N) bv = *(const float4*)(Bw + (k0 + bk) * N + n0 + bn);
        __syncthreads();
        As[ak + 0][am] = av.x;
        As[ak + 1][am] = av.y;
        As[ak + 2][am] = av.z;
        As[ak + 3][am] = av.w;
        *(float4*)&Bs[bk][bn] = bv;
        __syncthreads();
#pragma unroll
        for (int kk = 0; kk < 16; ++kk) {
            float4 a = *(const float4*)&As[kk][ty * 4];
            float4 bb = *(const float4*)&Bs[kk][tx * 4];
            float aa[4] = {a.x, a.y, a.z, a.w};
            float bbb[4] = {bb.x, bb.y, bb.z, bb.w};
#pragma unroll
            for (int i = 0; i < 4; ++i)
#pragma unroll
                for (int j = 0; j < 4; ++j)
                    acc[i][j] = fmaf(aa[i], bbb[j], acc[i][j]);
        }
    }
#pragma unroll
    for (int i = 0; i < 4; ++i) {
        int m = m0 + ty * 4 + i;
#pragma unroll
        for (int j = 0; j < 4; ++j) {
            int n = n0 + tx * 4 + j;
            if (n < N) {
                float v = acc[i][j] + bias[n];
                if (ACT == 0) v = fmaxf(v, 0.f);
                else          v = 1.f / (1.f + expf(-v));
                C[m * N + n] = v;
            }
        }
    }
}

// --------------------------------------------------------------------------
extern "C" void kernel_launch(void* const* d_in, const int* in_sizes, int n_in,
                              void* d_out, int out_size, void* d_ws, size_t ws_size,
                              hipStream_t stream) {
    const float* x   = (const float*)d_in[0];
    const float* w1  = (const float*)d_in[1];
    const float* b1  = (const float*)d_in[2];
    const float* pw  = (const float*)d_in[3];
    const float* pb  = (const float*)d_in[4];
    const float* rw  = (const float*)d_in[5];
    const float* dw1 = (const float*)d_in[6];
    const float* db1 = (const float*)d_in[7];
    const float* dw2 = (const float*)d_in[8];
    const float* db2 = (const float*)d_in[9];
    const float* dw3 = (const float*)d_in[10];
    const float* db3 = (const float*)d_in[11];
    float* out = (float*)d_out;
    char* wsb  = (char*)d_ws;
    if (ws_size < (size_t)WS_BYTES) return;

    h16*   hhi  = (h16*)(wsb + OFFB_HHI);
    h16*   wthi = (h16*)(wsb + OFFB_WTHI);
    h16*   w1t  = (h16*)(wsb + OFFB_WT1);
    float* Cbuf = (float*)(wsb + OFFB_C);
    h16*   pri  = (h16*)(wsb + OFFB_PRI);
    h16*   ut   = (h16*)(wsb + OFFB_UT);
    float* vbuf = (float*)(wsb + OFFB_V);
    float* d1   = (float*)(wsb + OFFB_D1);
    float* d2   = (float*)(wsb + OFFB_D2);

    prep_k<<<18784, 256, 0, stream>>>(w1, pw, w1t, wthi, Cbuf);
    conv1_mfma<<<3200, 256, 0, stream>>>(x, w1t, b1, hhi);
    prim_gemm_mfma<<<2304, 512, 0, stream>>>(hhi, wthi, Cbuf);
    squash_k<<<2304, 256, 0, stream>>>(Cbuf, pb, ut); // h region dead now
    priors_k<<<1440, 256, 0, stream>>>(ut, rw, pri);
    routing2_k<<<5120, 384, 0, stream>>>(pri, vbuf);
    dec1_k<<<512, 512, 0, stream>>>(vbuf, dw1, db1, out, d1);
    dec_gemm<0><<<128, 256, 0, stream>>>(d1, dw2, db2, d2, 512, 1024, 512);
    dec_gemm<1><<<104, 256, 0, stream>>>(d2, dw3, db3, out + 5120, 512, 784, 1024);
}

// Round 3
// 847.432 us; speedup vs baseline: 1.0896x; 1.0896x over previous
//
#include <hip/hip_runtime.h>
#include <math.h>

// ---------------------------------------------------------------------------
// CapsuleNet forward (round 21): revert prim to round-19 shape (BM=BN=128,
// 256 thr, split-K x8, 323 us) — round-20's BN=256 regressed (387 us: atomics
// x2, FETCH barely moved, 8-wave barrier costlier, occupancy flat).
// Two new prim changes on top of round-19:
//  (1) T3/T4-lite: TRIPLE-buffered LDS + raw s_barrier + counted
//      s_waitcnt vmcnt(4) (never 0 in main loop) -> 2 iterations of
//      issue->use slack for global_load_lds instead of 1.
//      Safety: lgkmcnt(0) before barrier (my ds_reads retired before the
//      buffer is overwritten), "memory"-clobber asm + sched_barrier(0).
//  (2) XOR slot-swizzle (slot = quad ^ (row&3)) on the 16B k-chunks,
//      pre-applied to the per-lane GLOBAL source address (LDS dest stays
//      lane-linear per global_load_lds rules); ds_read side applies the
//      same XOR. 8-way -> 4-way bank pattern on frag reads.
// Everything else identical to round-19:
//  - conv1: MFMA implicit im2col                     [round 13]
//  - priors_k/routing2_k two-phase + it0 shortcut    [rounds 6/12/14]
//  - dec1 fused argmax+sparse GEMM, prep_k fused     [round 12]
// ---------------------------------------------------------------------------

typedef _Float16 h16;
typedef h16 frag8 __attribute__((ext_vector_type(8)));    // 8 halves = 16 B
typedef float f32x4 __attribute__((ext_vector_type(4)));

// workspace layout (BYTE offsets).
#define OFFB_HHI   0L             // 52428800 halves = 104857600 B
#define OFFB_WTHI  209715200L     // 5308416 halves = 10616832 B
#define OFFB_WT1   230948864L     // w1t: 24576 halves = 49152 B
#define OFFB_C     231031808L     // 4718592 floats -> end 249906176
#define WS_BYTES   249906176L
// aliased into dead h region after prim_gemm:
#define OFFB_PRI   0L             // 94371840 halves = 188743680 B (priors fp16)
#define OFFB_UT    188743680L     // 4718592 halves = 9437184 B -> OK
// aliased into dead wt region after prim_gemm:
#define OFFB_V     209715200L     // 81920 floats
#define OFFB_D1    210370560L     // 262144 floats
#define OFFB_D2    211419136L     // 524288 floats -> 213516288 OK

// async global->LDS, 16 B per lane. LDS dest must be lane-linear:
// lane i of a wave writes base + i*16 B.
#define GLL16(gp, lp)                                                        \
    __builtin_amdgcn_global_load_lds(                                        \
        (const __attribute__((address_space(1))) void*)(gp),                 \
        (__attribute__((address_space(3))) void*)(lp), 16, 0, 0)

// --------------------------------------------------------------------------
// prep: blocks 0..95: w1t[oc][96] fp16 (k-padded); 96..351: prim B^T fp16;
// 352..18783: zero C.
__global__ __launch_bounds__(256) void prep_k(const float* __restrict__ w1,
                                              const float* __restrict__ pw,
                                              h16* __restrict__ w1t,
                                              h16* __restrict__ whi,
                                              float* __restrict__ C) {
    __shared__ float s[2592];
    int bx = blockIdx.x, tid = threadIdx.x;
    if (bx < 96) {
        int k = bx, oc = tid;
        w1t[(long)oc * 96 + k] = (k < 81) ? (h16)w1[oc * 81 + k] : (h16)0.f;
    } else if (bx < 352) {
        int oc = bx - 96;
        long src0 = (long)oc * 20736, dst0 = src0;
        for (int ch = 0; ch < 8; ++ch) {
            int ic0 = ch * 32;
            __syncthreads();
            for (int e = tid; e < 2592; e += 256) s[e] = pw[src0 + ic0 * 81 + e];
            __syncthreads();
            for (int e = tid; e < 2592; e += 256) {
                int tap = e >> 5, icf = e & 31;
                whi[dst0 + tap * 256 + ic0 + icf] = (h16)s[icf * 81 + tap];
            }
        }
    } else {
        long i = (long)(bx - 352) * 256 + tid;   // 18432 blocks * 256 = 4718592
        C[i] = 0.f;
    }
}

// --------------------------------------------------------------------------
// conv1 as MFMA implicit-im2col GEMM. Grid 3200: nt = bx&1, mt = bx>>1.
#define CLDK 104
__global__ __launch_bounds__(256, 2) void conv1_mfma(const float* __restrict__ x,
                                                     const h16* __restrict__ w1t,
                                                     const float* __restrict__ bias,
                                                     h16* __restrict__ hhi) {
    __shared__ h16 Al[128 * CLDK];
    __shared__ h16 Bw[128 * CLDK];
    int tid = threadIdx.x;
    int bx = blockIdx.x;
    int nt = bx & 1, mt = bx >> 1;
    int n0 = nt * 128;

    for (int e = tid; e < 128 * 96; e += 256) {
        int oc = e / 96, k = e - (e / 96) * 96;
        Bw[oc * CLDK + k] = w1t[(long)(n0 + oc) * 96 + k];
    }
    for (int e = tid; e < 128 * 96; e += 256) {
        int ml = e / 96, k = e - (e / 96) * 96;
        int m = mt * 128 + ml;
        int b = m / 400, pix = m - b * 400;
        int oy = pix / 20, ox = pix - oy * 20;
        float v = 0.f;
        if (k < 81) {
            int ky = k / 9, kx = k - ky * 9;
            v = x[(long)b * 784 + (oy + ky) * 28 + (ox + kx)];
        }
        Al[ml * CLDK + k] = (h16)v;
    }
    __syncthreads();

    int wave = tid >> 6;
    int wm = wave >> 1, wn = wave & 1;
    int lane = tid & 63;
    int lm = lane & 15, quad = lane >> 4;

    f32x4 acc[4][4];
#pragma unroll
    for (int i = 0; i < 4; ++i)
#pragma unroll
        for (int j = 0; j < 4; ++j) acc[i][j] = (f32x4){0.f, 0.f, 0.f, 0.f};

#pragma unroll
    for (int ks = 0; ks < 3; ++ks) {
        int kc = ks * 32 + quad * 8;
        frag8 af[4], bf[4];
#pragma unroll
        for (int mi = 0; mi < 4; ++mi)
            af[mi] = *(const frag8*)&Al[(wm * 64 + mi * 16 + lm) * CLDK + kc];
#pragma unroll
        for (int ni = 0; ni < 4; ++ni)
            bf[ni] = *(const frag8*)&Bw[(wn * 64 + ni * 16 + lm) * CLDK + kc];
#pragma unroll
        for (int mi = 0; mi < 4; ++mi)
#pragma unroll
            for (int ni = 0; ni < 4; ++ni)
                acc[mi][ni] = __builtin_amdgcn_mfma_f32_16x16x32_f16(
                    af[mi], bf[ni], acc[mi][ni], 0, 0, 0);
    }

#pragma unroll
    for (int ni = 0; ni < 4; ++ni) {
        int oc = n0 + wn * 64 + ni * 16 + lm;
        float bv = bias[oc];
#pragma unroll
        for (int mi = 0; mi < 4; ++mi) {
            int m = mt * 128 + wm * 64 + mi * 16 + quad * 4;
#pragma unroll
            for (int r = 0; r < 4; ++r)
                hhi[(long)(m + r) * 256 + oc] = (h16)fmaxf(acc[mi][ni][r] + bv, 0.f);
        }
    }
}

// --------------------------------------------------------------------------
// prim conv MFMA GEMM (round 21): BM=128 BN=128 BK=32, split-K x8
// (kt = bx&7 -> XCD-pinned B slice). TRIPLE-buffered linear LDS staged by
// global_load_lds dwordx4; raw s_barrier + counted vmcnt(4) (2-iter slack);
// XOR slot-swizzle on 16B chunks (4-way instead of 8-way bank pattern).
// Atomic accumulate into zeroed C. 4 waves/EU.
#define PBUF 4096   // halves per buffer (128 rows x 32)
__global__ __launch_bounds__(256, 4) void prim_gemm_mfma(
        const h16* __restrict__ Ahi, const h16* __restrict__ Bhi,
        float* __restrict__ C) {
    __shared__ __align__(16) h16 As[3][PBUF];
    __shared__ __align__(16) h16 Bs[3][PBUF];
    int tid = threadIdx.x;
    int bx = blockIdx.x;                  // 2304 blocks
    int kt = bx & 7;
    int nt = (bx >> 3) & 1;
    int mt = bx >> 4;                     // 0..143
    int n0 = nt * 128;
    int kb0 = kt * 81;

    int wave = tid >> 6;
    int wm = wave >> 1, wn = wave & 1;
    int lane = tid & 63;
    int lm = lane & 15, quad = lane >> 4;

    // staging geometry: thread t writes LDS halves [t*8, t*8+8) (linear) in
    // each of 2 GLL16 rounds: round q covers row r = (t>>2)+q*64.
    // Slot swizzle: LDS[r][slot] holds global k-chunk (slot ^ (r&3)); dest
    // stays linear, the per-lane GLOBAL source picks the swizzled chunk.
    int r0 = tid >> 2;
    int c0 = (((tid & 3) ^ (r0 & 3))) * 8;   // swizzled source chunk (halves)
    long abase0, abase1, bbase0, bbase1;
    {
        int m = mt * 128 + r0;
        int b = m / 36, pos = m - b * 36;
        int oy = pos / 6, ox = pos - oy * 6;
        abase0 = ((long)(b * 20 + 2 * oy) * 20 + 2 * ox) * 256 + c0;
        m = mt * 128 + r0 + 64;
        b = m / 36; pos = m - b * 36;
        oy = pos / 6; ox = pos - oy * 6;
        abase1 = ((long)(b * 20 + 2 * oy) * 20 + 2 * ox) * 256 + c0;
        bbase0 = (long)(n0 + r0) * 20736 + c0;
        bbase1 = (long)(n0 + r0 + 64) * 20736 + c0;
    }
    h16* la = &As[0][tid * 8];
    h16* lb = &Bs[0][tid * 8];

    auto stage = [&](int buf, int kb) {
        // wave-uniform K-step decode (lands in SGPRs)
        int tap = kb >> 3;
        int ic0 = (kb & 7) << 5;
        int ky = tap / 9, kx = tap - ky * 9;
        long aoff = (long)(ky * 20 + kx) * 256 + ic0;
        long boff = (long)kb * 32;
        long lo = (long)buf * PBUF;
        GLL16(Ahi + abase0 + aoff, la + lo);
        GLL16(Ahi + abase1 + aoff, la + lo + 2048);
        GLL16(Bhi + bbase0 + boff, lb + lo);
        GLL16(Bhi + bbase1 + boff, lb + lo + 2048);
    };

    f32x4 acc[4][4];
#pragma unroll
    for (int i = 0; i < 4; ++i)
#pragma unroll
        for (int j = 0; j < 4; ++j) acc[i][j] = (f32x4){0.f, 0.f, 0.f, 0.f};

    // frag-read slot swizzle: row&3 == lm&3 for both A rows and B cols.
    int sa = ((quad ^ (lm & 3)) << 3);

    stage(0, kb0);
    stage(1, kb0 + 1);
    int cur = 0, sb = 2;
    for (int it = 0; it < 81; ++it) {
        // Counted drain (T4): keep the newest stage's 4 loads in flight;
        // wait only for the stage feeding buf[cur]. lgkmcnt(0): my ds_reads
        // of the buffer about to be overwritten have retired. Full drain
        // only on the last iteration.
        if (it < 80) asm volatile("s_waitcnt vmcnt(4) lgkmcnt(0)" ::: "memory");
        else         asm volatile("s_waitcnt vmcnt(0) lgkmcnt(0)" ::: "memory");
        __builtin_amdgcn_s_barrier();
        __builtin_amdgcn_sched_barrier(0);
        if (it + 2 < 81) {
            stage(sb, kb0 + it + 2);
            sb = (sb == 2) ? 0 : sb + 1;
        }

        frag8 ah[4], bh[4];
#pragma unroll
        for (int mi = 0; mi < 4; ++mi) {
            int row = wm * 64 + mi * 16 + lm;
            ah[mi] = *(const frag8*)&As[cur][row * 32 + sa];
        }
#pragma unroll
        for (int ni = 0; ni < 4; ++ni) {
            int col = wn * 64 + ni * 16 + lm;
            bh[ni] = *(const frag8*)&Bs[cur][col * 32 + sa];
        }
#pragma unroll
        for (int mi = 0; mi < 4; ++mi)
#pragma unroll
            for (int ni = 0; ni < 4; ++ni)
                acc[mi][ni] = __builtin_amdgcn_mfma_f32_16x16x32_f16(
                    ah[mi], bh[ni], acc[mi][ni], 0, 0, 0);
        cur = (cur == 2) ? 0 : cur + 1;
    }

#pragma unroll
    for (int ni = 0; ni < 4; ++ni) {
        int n = n0 + wn * 64 + ni * 16 + lm;
#pragma unroll
        for (int mi = 0; mi < 4; ++mi) {
            int m = mt * 128 + wm * 64 + mi * 16 + quad * 4;
#pragma unroll
            for (int r = 0; r < 4; ++r)
                atomicAdd(&C[(long)(m + r) * 256 + n], acc[mi][ni][r]);
        }
    }
}

// --------------------------------------------------------------------------
// squash: C[(b*36+pos)][256] (+bias) -> ut[n][b][8] fp16, n = ci*36+pos.
__global__ void squash_k(const float* __restrict__ C,
                         const float* __restrict__ bias,
                         h16* __restrict__ ut) {
    int t = blockIdx.x * 256 + threadIdx.x;          // 589824 exact
    int row = t >> 5;                                 // (b*36+pos)
    int ci = t & 31;
    int b = row / 36, pos = row - b * 36;
    const float* src = C + (long)row * 256 + ci;
    float v[8]; float sn = 0.f;
#pragma unroll
    for (int i = 0; i < 8; ++i) {
        v[i] = src[i * 32] + bias[ci + i * 32];
        sn = fmaf(v[i], v[i], sn);
    }
    float scale = (sn / (1.f + sn)) / sqrtf(sn);
    frag8 o;
#pragma unroll
    for (int i = 0; i < 8; ++i) o[i] = (h16)(v[i] * scale);
    *(frag8*)(ut + ((long)(ci * 36 + pos) * 512 + b) * 8) = o;
}

// --------------------------------------------------------------------------
// Phase A: priors[c,b,n,:16] = ut[n,b,:8] @ rw[c,n,:8,:16], fp16 out.
__global__ __launch_bounds__(256) void priors_k(const h16* __restrict__ ut,
                                                const float* __restrict__ rw,
                                                h16* __restrict__ priors) {
    int bid = blockIdx.x;                 // 1440 = 10 c * 144 n-groups
    int c = bid / 144, ng = bid - c * 144;
    int n0 = ng * 8;
    __shared__ float w[8][132];
    int tid = threadIdx.x;
    for (int e = tid; e < 1024; e += 256)
        w[e >> 7][e & 127] = rw[((long)c * 1152 + n0 + (e >> 7)) * 128 + (e & 127)];
    __syncthreads();
    int nl = tid & 7, bl = tid >> 3;      // bl 0..31
    int n = n0 + nl;
    for (int ch = 0; ch < 16; ++ch) {
        int b = ch * 32 + bl;
        frag8 uv = *(const frag8*)(ut + ((long)n * 512 + b) * 8);
        float uu[8];
#pragma unroll
        for (int i = 0; i < 8; ++i) uu[i] = (float)uv[i];
        float o[16];
#pragma unroll
        for (int j = 0; j < 16; ++j) o[j] = 0.f;
#pragma unroll
        for (int i = 0; i < 8; ++i)
#pragma unroll
            for (int j = 0; j < 16; ++j)
                o[j] = fmaf(uu[i], w[nl][i * 16 + j], o[j]);
        frag8 p0, p1;
#pragma unroll
        for (int j = 0; j < 8; ++j) { p0[j] = (h16)o[j]; p1[j] = (h16)o[j + 8]; }
        h16* dst = priors + ((long)(c * 512 + b) * 1152 + n) * 16;
        *(frag8*)dst = p0;
        *(frag8*)(dst + 8) = p1;
    }
}

// --------------------------------------------------------------------------
// Phase B: 3-iter routing. Block per (c,b). Iteration 0 uses the exact
// uniform-softmax shortcut (initial logits identically 0 -> probs = 1/1152).
__global__ __launch_bounds__(384) void routing2_k(const h16* __restrict__ priors,
                                                  float* __restrict__ vbuf) {
    int c = blockIdx.x >> 9;
    int b = blockIdx.x & 511;
    int tid = threadIdx.x;
    int wid = tid >> 6;
    int lane = tid & 63;
    __shared__ float wred[6][20];

    float pr[3][16];
#pragma unroll
    for (int r = 0; r < 3; ++r) {
        int n = tid + r * 384;
        const h16* pp = priors + ((long)(c * 512 + b) * 1152 + n) * 16;
        frag8 p0 = *(const frag8*)pp;
        frag8 p1 = *(const frag8*)(pp + 8);
#pragma unroll
        for (int o = 0; o < 8; ++o) { pr[r][o] = (float)p0[o]; pr[r][o + 8] = (float)p1[o]; }
    }

    float l0 = 0.f, l1 = 0.f, l2 = 0.f;
    float vout[16];

    // ---- iteration 0: probs uniform = 1/1152 ----
    {
        float red[16];
#pragma unroll
        for (int o = 0; o < 16; ++o) red[o] = pr[0][o] + pr[1][o] + pr[2][o];
#pragma unroll
        for (int o = 0; o < 16; ++o) {
#pragma unroll
            for (int m = 32; m >= 1; m >>= 1) red[o] += __shfl_xor(red[o], m);
        }
        if (lane == 0) {
#pragma unroll
            for (int o = 0; o < 16; ++o) wred[wid][o] = red[o];
        }
        __syncthreads();
        float inv = 1.f / 1152.f;
        float sn = 0.f;
        float sv[16];
#pragma unroll
        for (int o = 0; o < 16; ++o) {
            float tacc = wred[0][o];
#pragma unroll
            for (int w = 1; w < 6; ++w) tacc += wred[w][o];
            sv[o] = tacc * inv;
            sn = fmaf(sv[o], sv[o], sn);
        }
        float scale = (sn / (1.f + sn)) / sqrtf(sn);
#pragma unroll
        for (int o = 0; o < 16; ++o) vout[o] = sv[o] * scale;
        float d0 = 0.f, d1 = 0.f, d2 = 0.f;
#pragma unroll
        for (int o = 0; o < 16; ++o) {
            d0 = fmaf(pr[0][o], vout[o], d0);
            d1 = fmaf(pr[1][o], vout[o], d1);
            d2 = fmaf(pr[2][o], vout[o], d2);
        }
        l0 = d0; l1 = d1; l2 = d2;
        __syncthreads();                 // wred reused next iteration
    }

    // ---- iterations 1,2: full softmax path ----
    for (int it = 1; it < 3; ++it) {
        float lm = fmaxf(fmaxf(l0, l1), l2);
#pragma unroll
        for (int m = 32; m >= 1; m >>= 1) lm = fmaxf(lm, __shfl_xor(lm, m));
        if (lane == 0) wred[wid][17] = lm;
        __syncthreads();
        float maxv = wred[0][17];
#pragma unroll
        for (int w = 1; w < 6; ++w) maxv = fmaxf(maxv, wred[w][17]);

        float e0 = expf(l0 - maxv), e1 = expf(l1 - maxv), e2 = expf(l2 - maxv);
        float red[17];
#pragma unroll
        for (int o = 0; o < 16; ++o)
            red[o] = fmaf(e0, pr[0][o], fmaf(e1, pr[1][o], e2 * pr[2][o]));
        red[16] = e0 + e1 + e2;
#pragma unroll
        for (int o = 0; o < 17; ++o) {
#pragma unroll
            for (int m = 32; m >= 1; m >>= 1) red[o] += __shfl_xor(red[o], m);
        }
        __syncthreads();
        if (lane == 0) {
#pragma unroll
            for (int o = 0; o < 17; ++o) wred[wid][o] = red[o];
        }
        __syncthreads();
        float sv[17];
#pragma unroll
        for (int o = 0; o < 17; ++o) {
            float tacc = wred[0][o];
#pragma unroll
            for (int w = 1; w < 6; ++w) tacc += wred[w][o];
            sv[o] = tacc;
        }
        float inv = 1.f / sv[16];
        float sn = 0.f;
#pragma unroll
        for (int o = 0; o < 16; ++o) { float s = sv[o] * inv; sn = fmaf(s, s, sn); }
        float scale = (sn / (1.f + sn)) / sqrtf(sn);
#pragma unroll
        for (int o = 0; o < 16; ++o) vout[o] = sv[o] * inv * scale;

        if (it < 2) {
            float d0 = 0.f, d1 = 0.f, d2 = 0.f;
#pragma unroll
            for (int o = 0; o < 16; ++o) {
                d0 = fmaf(pr[0][o], vout[o], d0);
                d1 = fmaf(pr[1][o], vout[o], d1);
                d2 = fmaf(pr[2][o], vout[o], d2);
            }
            l0 += d0; l1 += d1; l2 += d2;
        }
    }
    if (tid < 16) vbuf[(b * 10 + c) * 16 + tid] = vout[tid];
}

// --------------------------------------------------------------------------
// dec1: fused classes/argmax/y_pred + sparse masked GEMM (K=16 of 160).
__global__ __launch_bounds__(512) void dec1_k(const float* __restrict__ vbuf,
                                              const float* __restrict__ dw1,
                                              const float* __restrict__ db1,
                                              float* __restrict__ out,
                                              float* __restrict__ d1) {
    __shared__ float sv[160];
    __shared__ float scls[10];
    __shared__ int sbest;
    int b = blockIdx.x, tid = threadIdx.x;
    if (tid < 160) sv[tid] = vbuf[b * 160 + tid];
    __syncthreads();
    if (tid < 10) {
        float sn = 0.f;
#pragma unroll
        for (int o = 0; o < 16; ++o) { float v = sv[tid * 16 + o]; sn = fmaf(v, v, sn); }
        scls[tid] = sqrtf(sn);
    }
    __syncthreads();
    if (tid == 0) {
        int best = 0; float bv = scls[0];
#pragma unroll
        for (int cc = 1; cc < 10; ++cc) if (scls[cc] > bv) { bv = scls[cc]; best = cc; }
        sbest = best;
    }
    __syncthreads();
    int best = sbest;
    if (tid < 10) {
        out[b * 10 + tid] = (tid == best) ? 1.f : 0.f;          // y_pred
        out[406528 + b * 10 + tid] = scls[tid];                 // classes
    }
    float acc = db1[tid];
    const float* wrow = dw1 + (long)best * 16 * 512;
#pragma unroll
    for (int i = 0; i < 16; ++i)
        acc = fmaf(sv[best * 16 + i], wrow[i * 512 + tid], acc);
    d1[(long)b * 512 + tid] = fmaxf(acc, 0.f);
}

// --------------------------------------------------------------------------
template <int ACT>
__global__ __launch_bounds__(256) void dec_gemm(const float* __restrict__ A,
                                                const float* __restrict__ Bw,
                                                const float* __restrict__ bias,
                                                float* __restrict__ C,
                                                int M, int N, int K) {
    __shared__ float As[16][68];
    __shared__ float Bs[16][68];
    int ntiles = (N + 63) >> 6;
    int mt = blockIdx.x / ntiles, nt = blockIdx.x - mt * ntiles;
    int m0 = mt * 64, n0 = nt * 64;
    int tid = threadIdx.x;
    int tx = tid & 15, ty = tid >> 4;
    int am = tid >> 2, ak = (tid & 3) * 4;
    int bk = tid >> 4, bn = (tid & 15) * 4;
    float acc[4][4];
#pragma unroll
    for (int i = 0; i < 4; ++i)
#pragma unroll
        for (int j = 0; j < 4; ++j) acc[i][j] = 0.f;

    for (int k0 = 0; k0 < K; k0 += 16) {
        float4 av = *(const float4*)(A + (m0 + am) * K + k0 + ak);
        float4 bv = make_float4(0.f, 0.f, 0.f, 0.f);
        if (n0 + bn < N) bv = *(const float4*)(Bw + (k0 + bk) * N + n0 + bn);
        __syncthreads();
        As[ak + 0][am] = av.x;
        As[ak + 1][am] = av.y;
        As[ak + 2][am] = av.z;
        As[ak + 3][am] = av.w;
        *(float4*)&Bs[bk][bn] = bv;
        __syncthreads();
#pragma unroll
        for (int kk = 0; kk < 16; ++kk) {
            float4 a = *(const float4*)&As[kk][ty * 4];
            float4 bb = *(const float4*)&Bs[kk][tx * 4];
            float aa[4] = {a.x, a.y, a.z, a.w};
            float bbb[4] = {bb.x, bb.y, bb.z, bb.w};
#pragma unroll
            for (int i = 0; i < 4; ++i)
#pragma unroll
                for (int j = 0; j < 4; ++j)
                    acc[i][j] = fmaf(aa[i], bbb[j], acc[i][j]);
        }
    }
#pragma unroll
    for (int i = 0; i < 4; ++i) {
        int m = m0 + ty * 4 + i;
#pragma unroll
        for (int j = 0; j < 4; ++j) {
            int n = n0 + tx * 4 + j;
            if (n < N) {
                float v = acc[i][j] + bias[n];
                if (ACT == 0) v = fmaxf(v, 0.f);
                else          v = 1.f / (1.f + expf(-v));
                C[m * N + n] = v;
            }
        }
    }
}

// --------------------------------------------------------------------------
extern "C" void kernel_launch(void* const* d_in, const int* in_sizes, int n_in,
                              void* d_out, int out_size, void* d_ws, size_t ws_size,
                              hipStream_t stream) {
    const float* x   = (const float*)d_in[0];
    const float* w1  = (const float*)d_in[1];
    const float* b1  = (const float*)d_in[2];
    const float* pw  = (const float*)d_in[3];
    const float* pb  = (const float*)d_in[4];
    const float* rw  = (const float*)d_in[5];
    const float* dw1 = (const float*)d_in[6];
    const float* db1 = (const float*)d_in[7];
    const float* dw2 = (const float*)d_in[8];
    const float* db2 = (const float*)d_in[9];
    const float* dw3 = (const float*)d_in[10];
    const float* db3 = (const float*)d_in[11];
    float* out = (float*)d_out;
    char* wsb  = (char*)d_ws;
    if (ws_size < (size_t)WS_BYTES) return;

    h16*   hhi  = (h16*)(wsb + OFFB_HHI);
    h16*   wthi = (h16*)(wsb + OFFB_WTHI);
    h16*   w1t  = (h16*)(wsb + OFFB_WT1);
    float* Cbuf = (float*)(wsb + OFFB_C);
    h16*   pri  = (h16*)(wsb + OFFB_PRI);
    h16*   ut   = (h16*)(wsb + OFFB_UT);
    float* vbuf = (float*)(wsb + OFFB_V);
    float* d1   = (float*)(wsb + OFFB_D1);
    float* d2   = (float*)(wsb + OFFB_D2);

    prep_k<<<18784, 256, 0, stream>>>(w1, pw, w1t, wthi, Cbuf);
    conv1_mfma<<<3200, 256, 0, stream>>>(x, w1t, b1, hhi);
    prim_gemm_mfma<<<2304, 256, 0, stream>>>(hhi, wthi, Cbuf);
    squash_k<<<2304, 256, 0, stream>>>(Cbuf, pb, ut); // h region dead now
    priors_k<<<1440, 256, 0, stream>>>(ut, rw, pri);
    routing2_k<<<5120, 384, 0, stream>>>(pri, vbuf);
    dec1_k<<<512, 512, 0, stream>>>(vbuf, dw1, db1, out, d1);
    dec_gemm<0><<<128, 256, 0, stream>>>(d1, dw2, db2, d2, 512, 1024, 512);
    dec_gemm<1><<<104, 256, 0, stream>>>(d2, dw3, db3, out + 5120, 512, 784, 1024);
}

// Round 4
// 816.141 us; speedup vs baseline: 1.1314x; 1.0383x over previous
//
#include <hip/hip_runtime.h>
#include <math.h>

// ---------------------------------------------------------------------------
// CapsuleNet forward (round 22):
//  - prim: EXACT round-19 revert (323 us measured; dbuf global_load_lds,
//    1 barrier/K-step). Round-21 learnings: (a) chunk-XOR swizzle left
//    SQ_LDS_BANK_CONFLICT bit-identical -> b128 frag reads are at the
//    256-dword/32-bank structural floor, not fixable; (b) triple-buffer +
//    counted vmcnt(4) neutral (occ 38->32 from 48KB LDS ate the gain).
//    Prim is plateaued; do not touch further without a new mechanism.
//  - conv1 REWRITTEN (suspected #2 hotspot, never visible in top-5):
//    (1) im2col staging per (ml,ky) pair: address div once per 9
//        contiguous x floats (was: div per element, 48 scalar gathers);
//    (2) operand-swapped MFMA (mfma(bf,af)) -> lane owns 4 consecutive oc
//        at fixed m -> 8B h16x4 epilogue stores (was: 64 scalar 2B stores);
//    (3) frag reads/MFMA count unchanged.
//  Everything else identical to round-19:
//  - priors_k/routing2_k two-phase + it0 shortcut    [rounds 6/12/14]
//  - dec1 fused argmax+sparse GEMM, prep_k fused     [round 12]
// ---------------------------------------------------------------------------

typedef _Float16 h16;
typedef h16 frag8 __attribute__((ext_vector_type(8)));    // 8 halves = 16 B
typedef h16 h16x4 __attribute__((ext_vector_type(4)));    // 4 halves = 8 B
typedef float f32x4 __attribute__((ext_vector_type(4)));

// workspace layout (BYTE offsets).
#define OFFB_HHI   0L             // 52428800 halves = 104857600 B
#define OFFB_WTHI  209715200L     // 5308416 halves = 10616832 B
#define OFFB_WT1   230948864L     // w1t: 24576 halves = 49152 B
#define OFFB_C     231031808L     // 4718592 floats -> end 249906176
#define WS_BYTES   249906176L
// aliased into dead h region after prim_gemm:
#define OFFB_PRI   0L             // 94371840 halves = 188743680 B (priors fp16)
#define OFFB_UT    188743680L     // 4718592 halves = 9437184 B -> OK
// aliased into dead wt region after prim_gemm:
#define OFFB_V     209715200L     // 81920 floats
#define OFFB_D1    210370560L     // 262144 floats
#define OFFB_D2    211419136L     // 524288 floats -> 213516288 OK

// async global->LDS, 16 B per lane. LDS dest must be lane-linear:
// lane i of a wave writes base + i*16 B.
#define GLL16(gp, lp)                                                        \
    __builtin_amdgcn_global_load_lds(                                        \
        (const __attribute__((address_space(1))) void*)(gp),                 \
        (__attribute__((address_space(3))) void*)(lp), 16, 0, 0)

// --------------------------------------------------------------------------
// prep: blocks 0..95: w1t[oc][96] fp16 (k-padded); 96..351: prim B^T fp16;
// 352..18783: zero C.
__global__ __launch_bounds__(256) void prep_k(const float* __restrict__ w1,
                                              const float* __restrict__ pw,
                                              h16* __restrict__ w1t,
                                              h16* __restrict__ whi,
                                              float* __restrict__ C) {
    __shared__ float s[2592];
    int bx = blockIdx.x, tid = threadIdx.x;
    if (bx < 96) {
        int k = bx, oc = tid;
        w1t[(long)oc * 96 + k] = (k < 81) ? (h16)w1[oc * 81 + k] : (h16)0.f;
    } else if (bx < 352) {
        int oc = bx - 96;
        long src0 = (long)oc * 20736, dst0 = src0;
        for (int ch = 0; ch < 8; ++ch) {
            int ic0 = ch * 32;
            __syncthreads();
            for (int e = tid; e < 2592; e += 256) s[e] = pw[src0 + ic0 * 81 + e];
            __syncthreads();
            for (int e = tid; e < 2592; e += 256) {
                int tap = e >> 5, icf = e & 31;
                whi[dst0 + tap * 256 + ic0 + icf] = (h16)s[icf * 81 + tap];
            }
        }
    } else {
        long i = (long)(bx - 352) * 256 + tid;   // 18432 blocks * 256 = 4718592
        C[i] = 0.f;
    }
}

// --------------------------------------------------------------------------
// conv1 as MFMA implicit-im2col GEMM. Grid 3200: nt = bx&1, mt = bx>>1.
// Round 22: pair-vectorized A-staging + operand-swapped vector epilogue.
#define CLDK 104
__global__ __launch_bounds__(256, 2) void conv1_mfma(const float* __restrict__ x,
                                                     const h16* __restrict__ w1t,
                                                     const float* __restrict__ bias,
                                                     h16* __restrict__ hhi) {
    __shared__ h16 Al[128 * CLDK];
    __shared__ h16 Bw[128 * CLDK];
    int tid = threadIdx.x;
    int bx = blockIdx.x;
    int nt = bx & 1, mt = bx >> 1;
    int n0 = nt * 128;

    // B stage: 128 oc x 96 k (unchanged).
    for (int e = tid; e < 128 * 96; e += 256) {
        int oc = e / 96, k = e - (e / 96) * 96;
        Bw[oc * CLDK + k] = w1t[(long)(n0 + oc) * 96 + k];
    }
    // A stage: one (ml, ky) pair per step -> 9 contiguous x floats; the
    // per-row address math (div 400 / div 20) runs once per 9 elements.
    for (int p = tid; p < 128 * 9; p += 256) {
        int ml = p / 9, ky = p - (p / 9) * 9;
        int m = mt * 128 + ml;
        int b = m / 400, pix = m - b * 400;
        int oy = pix / 20, ox = pix - oy * 20;
        const float* xs = x + (long)b * 784 + (oy + ky) * 28 + ox;
        h16* dst = &Al[ml * CLDK + ky * 9];
#pragma unroll
        for (int kx = 0; kx < 9; ++kx) dst[kx] = (h16)xs[kx];
    }
    // zero the k = 81..95 pad (MFMA reads through k=95).
    for (int e = tid; e < 128 * 16; e += 256) {
        int ml = e >> 4, kz = 81 + (e & 15);
        if (kz < 96) Al[ml * CLDK + kz] = (h16)0.f;
    }
    __syncthreads();

    int wave = tid >> 6;
    int wm = wave >> 1, wn = wave & 1;
    int lane = tid & 63;
    int lm = lane & 15, quad = lane >> 4;

    f32x4 acc[4][4];   // acc[ni][mi]: D rows = oc (quad*4+r), cols = m (lm)
#pragma unroll
    for (int i = 0; i < 4; ++i)
#pragma unroll
        for (int j = 0; j < 4; ++j) acc[i][j] = (f32x4){0.f, 0.f, 0.f, 0.f};

#pragma unroll
    for (int ks = 0; ks < 3; ++ks) {
        int kc = ks * 32 + quad * 8;
        frag8 af[4], bf[4];
#pragma unroll
        for (int mi = 0; mi < 4; ++mi)
            af[mi] = *(const frag8*)&Al[(wm * 64 + mi * 16 + lm) * CLDK + kc];
#pragma unroll
        for (int ni = 0; ni < 4; ++ni)
            bf[ni] = *(const frag8*)&Bw[(wn * 64 + ni * 16 + lm) * CLDK + kc];
        // operand swap: first operand's lm-space (oc) -> D rows (quad*4+r),
        // second operand's lm-space (m) -> D cols (lm).
#pragma unroll
        for (int ni = 0; ni < 4; ++ni)
#pragma unroll
            for (int mi = 0; mi < 4; ++mi)
                acc[ni][mi] = __builtin_amdgcn_mfma_f32_16x16x32_f16(
                    bf[ni], af[mi], acc[ni][mi], 0, 0, 0);
    }

    // epilogue: lane owns oc = ocb..ocb+3 at fixed m -> one 8B store per
    // (ni,mi). Lanes {lm fixed, quad 0..3} form 32B contiguous segments.
#pragma unroll
    for (int ni = 0; ni < 4; ++ni) {
        int ocb = n0 + wn * 64 + ni * 16 + quad * 4;
        float4 bv = *(const float4*)(bias + ocb);
#pragma unroll
        for (int mi = 0; mi < 4; ++mi) {
            int m = mt * 128 + wm * 64 + mi * 16 + lm;
            h16x4 o;
            o[0] = (h16)fmaxf(acc[ni][mi][0] + bv.x, 0.f);
            o[1] = (h16)fmaxf(acc[ni][mi][1] + bv.y, 0.f);
            o[2] = (h16)fmaxf(acc[ni][mi][2] + bv.z, 0.f);
            o[3] = (h16)fmaxf(acc[ni][mi][3] + bv.w, 0.f);
            *(h16x4*)(hhi + (long)m * 256 + ocb) = o;
        }
    }
}

// --------------------------------------------------------------------------
// prim conv MFMA GEMM (round-19 exact, 323 us): BM=128 BN=128 BK=32,
// split-K x8 (kt = bx&7 -> XCD-pinned B slice). Staging via global_load_lds
// dwordx4 into double-buffered LINEAR LDS [128][32]; one barrier per K-step.
// Atomic accumulate into zeroed C. 4 waves/EU.
__global__ __launch_bounds__(256, 4) void prim_gemm_mfma(
        const h16* __restrict__ Ahi, const h16* __restrict__ Bhi,
        float* __restrict__ C) {
    __shared__ __align__(16) h16 As[2][128 * 32];
    __shared__ __align__(16) h16 Bs[2][128 * 32];
    int tid = threadIdx.x;
    int bx = blockIdx.x;                  // 2304 blocks
    int kt = bx & 7;
    int nt = (bx >> 3) & 1;
    int mt = bx >> 4;                     // 0..143
    int n0 = nt * 128;
    int kb0 = kt * 81;

    int wave = tid >> 6;
    int wm = wave >> 1, wn = wave & 1;
    int lane = tid & 63;
    int lm = lane & 15, quad = lane >> 4;

    // staging geometry: thread t, chunk q in {0,1} covers LDS halves
    // [t*8 + q*2048, +8)  ->  row r = (t>>2) + q*64, col c = (t&3)*8.
    int c0 = (tid & 3) * 8;
    int r0 = tid >> 2;
    long abase0, abase1, bbase0, bbase1;
    {
        int m = mt * 128 + r0;
        int b = m / 36, pos = m - b * 36;
        int oy = pos / 6, ox = pos - oy * 6;
        abase0 = ((long)(b * 20 + 2 * oy) * 20 + 2 * ox) * 256 + c0;
        m = mt * 128 + r0 + 64;
        b = m / 36; pos = m - b * 36;
        oy = pos / 6; ox = pos - oy * 6;
        abase1 = ((long)(b * 20 + 2 * oy) * 20 + 2 * ox) * 256 + c0;
        bbase0 = (long)(n0 + r0) * 20736 + c0;
        bbase1 = (long)(n0 + r0 + 64) * 20736 + c0;
    }
    h16* la = &As[0][tid * 8];
    h16* lb = &Bs[0][tid * 8];

    auto stage = [&](int buf, int kb) {
        // wave-uniform K-step decode (lands in SGPRs)
        int tap = kb >> 3;
        int ic0 = (kb & 7) << 5;
        int ky = tap / 9, kx = tap - ky * 9;
        long aoff = (long)(ky * 20 + kx) * 256 + ic0;
        long boff = (long)kb * 32;
        long lo = (long)buf * 4096;       // halves per buffer
        GLL16(Ahi + abase0 + aoff, la + lo);
        GLL16(Ahi + abase1 + aoff, la + lo + 2048);
        GLL16(Bhi + bbase0 + boff, lb + lo);
        GLL16(Bhi + bbase1 + boff, lb + lo + 2048);
    };

    f32x4 acc[4][4];
#pragma unroll
    for (int i = 0; i < 4; ++i)
#pragma unroll
        for (int j = 0; j < 4; ++j) acc[i][j] = (f32x4){0.f, 0.f, 0.f, 0.f};

    stage(0, kb0);
    for (int it = 0; it < 81; ++it) {
        int cur = it & 1;
        // one barrier per K-step: drains vmcnt (buf[cur] staged) and lgkm
        // (prev iter's ds_reads of buf[cur^1] done before we overwrite it).
        __syncthreads();
        if (it + 1 < 81) stage(cur ^ 1, kb0 + it + 1);

        frag8 ah[4], bh[4];
#pragma unroll
        for (int mi = 0; mi < 4; ++mi) {
            int row = wm * 64 + mi * 16 + lm;
            ah[mi] = *(const frag8*)&As[cur][row * 32 + quad * 8];
        }
#pragma unroll
        for (int ni = 0; ni < 4; ++ni) {
            int col = wn * 64 + ni * 16 + lm;
            bh[ni] = *(const frag8*)&Bs[cur][col * 32 + quad * 8];
        }
#pragma unroll
        for (int mi = 0; mi < 4; ++mi)
#pragma unroll
            for (int ni = 0; ni < 4; ++ni)
                acc[mi][ni] = __builtin_amdgcn_mfma_f32_16x16x32_f16(
                    ah[mi], bh[ni], acc[mi][ni], 0, 0, 0);
    }

#pragma unroll
    for (int ni = 0; ni < 4; ++ni) {
        int n = n0 + wn * 64 + ni * 16 + lm;
#pragma unroll
        for (int mi = 0; mi < 4; ++mi) {
            int m = mt * 128 + wm * 64 + mi * 16 + quad * 4;
#pragma unroll
            for (int r = 0; r < 4; ++r)
                atomicAdd(&C[(long)(m + r) * 256 + n], acc[mi][ni][r]);
        }
    }
}

// --------------------------------------------------------------------------
// squash: C[(b*36+pos)][256] (+bias) -> ut[n][b][8] fp16, n = ci*36+pos.
__global__ void squash_k(const float* __restrict__ C,
                         const float* __restrict__ bias,
                         h16* __restrict__ ut) {
    int t = blockIdx.x * 256 + threadIdx.x;          // 589824 exact
    int row = t >> 5;                                 // (b*36+pos)
    int ci = t & 31;
    int b = row / 36, pos = row - b * 36;
    const float* src = C + (long)row * 256 + ci;
    float v[8]; float sn = 0.f;
#pragma unroll
    for (int i = 0; i < 8; ++i) {
        v[i] = src[i * 32] + bias[ci + i * 32];
        sn = fmaf(v[i], v[i], sn);
    }
    float scale = (sn / (1.f + sn)) / sqrtf(sn);
    frag8 o;
#pragma unroll
    for (int i = 0; i < 8; ++i) o[i] = (h16)(v[i] * scale);
    *(frag8*)(ut + ((long)(ci * 36 + pos) * 512 + b) * 8) = o;
}

// --------------------------------------------------------------------------
// Phase A: priors[c,b,n,:16] = ut[n,b,:8] @ rw[c,n,:8,:16], fp16 out.
__global__ __launch_bounds__(256) void priors_k(const h16* __restrict__ ut,
                                                const float* __restrict__ rw,
                                                h16* __restrict__ priors) {
    int bid = blockIdx.x;                 // 1440 = 10 c * 144 n-groups
    int c = bid / 144, ng = bid - c * 144;
    int n0 = ng * 8;
    __shared__ float w[8][132];
    int tid = threadIdx.x;
    for (int e = tid; e < 1024; e += 256)
        w[e >> 7][e & 127] = rw[((long)c * 1152 + n0 + (e >> 7)) * 128 + (e & 127)];
    __syncthreads();
    int nl = tid & 7, bl = tid >> 3;      // bl 0..31
    int n = n0 + nl;
    for (int ch = 0; ch < 16; ++ch) {
        int b = ch * 32 + bl;
        frag8 uv = *(const frag8*)(ut + ((long)n * 512 + b) * 8);
        float uu[8];
#pragma unroll
        for (int i = 0; i < 8; ++i) uu[i] = (float)uv[i];
        float o[16];
#pragma unroll
        for (int j = 0; j < 16; ++j) o[j] = 0.f;
#pragma unroll
        for (int i = 0; i < 8; ++i)
#pragma unroll
            for (int j = 0; j < 16; ++j)
                o[j] = fmaf(uu[i], w[nl][i * 16 + j], o[j]);
        frag8 p0, p1;
#pragma unroll
        for (int j = 0; j < 8; ++j) { p0[j] = (h16)o[j]; p1[j] = (h16)o[j + 8]; }
        h16* dst = priors + ((long)(c * 512 + b) * 1152 + n) * 16;
        *(frag8*)dst = p0;
        *(frag8*)(dst + 8) = p1;
    }
}

// --------------------------------------------------------------------------
// Phase B: 3-iter routing. Block per (c,b). Iteration 0 uses the exact
// uniform-softmax shortcut (initial logits identically 0 -> probs = 1/1152).
__global__ __launch_bounds__(384) void routing2_k(const h16* __restrict__ priors,
                                                  float* __restrict__ vbuf) {
    int c = blockIdx.x >> 9;
    int b = blockIdx.x & 511;
    int tid = threadIdx.x;
    int wid = tid >> 6;
    int lane = tid & 63;
    __shared__ float wred[6][20];

    float pr[3][16];
#pragma unroll
    for (int r = 0; r < 3; ++r) {
        int n = tid + r * 384;
        const h16* pp = priors + ((long)(c * 512 + b) * 1152 + n) * 16;
        frag8 p0 = *(const frag8*)pp;
        frag8 p1 = *(const frag8*)(pp + 8);
#pragma unroll
        for (int o = 0; o < 8; ++o) { pr[r][o] = (float)p0[o]; pr[r][o + 8] = (float)p1[o]; }
    }

    float l0 = 0.f, l1 = 0.f, l2 = 0.f;
    float vout[16];

    // ---- iteration 0: probs uniform = 1/1152 ----
    {
        float red[16];
#pragma unroll
        for (int o = 0; o < 16; ++o) red[o] = pr[0][o] + pr[1][o] + pr[2][o];
#pragma unroll
        for (int o = 0; o < 16; ++o) {
#pragma unroll
            for (int m = 32; m >= 1; m >>= 1) red[o] += __shfl_xor(red[o], m);
        }
        if (lane == 0) {
#pragma unroll
            for (int o = 0; o < 16; ++o) wred[wid][o] = red[o];
        }
        __syncthreads();
        float inv = 1.f / 1152.f;
        float sn = 0.f;
        float sv[16];
#pragma unroll
        for (int o = 0; o < 16; ++o) {
            float tacc = wred[0][o];
#pragma unroll
            for (int w = 1; w < 6; ++w) tacc += wred[w][o];
            sv[o] = tacc * inv;
            sn = fmaf(sv[o], sv[o], sn);
        }
        float scale = (sn / (1.f + sn)) / sqrtf(sn);
#pragma unroll
        for (int o = 0; o < 16; ++o) vout[o] = sv[o] * scale;
        float d0 = 0.f, d1 = 0.f, d2 = 0.f;
#pragma unroll
        for (int o = 0; o < 16; ++o) {
            d0 = fmaf(pr[0][o], vout[o], d0);
            d1 = fmaf(pr[1][o], vout[o], d1);
            d2 = fmaf(pr[2][o], vout[o], d2);
        }
        l0 = d0; l1 = d1; l2 = d2;
        __syncthreads();                 // wred reused next iteration
    }

    // ---- iterations 1,2: full softmax path ----
    for (int it = 1; it < 3; ++it) {
        float lm = fmaxf(fmaxf(l0, l1), l2);
#pragma unroll
        for (int m = 32; m >= 1; m >>= 1) lm = fmaxf(lm, __shfl_xor(lm, m));
        if (lane == 0) wred[wid][17] = lm;
        __syncthreads();
        float maxv = wred[0][17];
#pragma unroll
        for (int w = 1; w < 6; ++w) maxv = fmaxf(maxv, wred[w][17]);

        float e0 = expf(l0 - maxv), e1 = expf(l1 - maxv), e2 = expf(l2 - maxv);
        float red[17];
#pragma unroll
        for (int o = 0; o < 16; ++o)
            red[o] = fmaf(e0, pr[0][o], fmaf(e1, pr[1][o], e2 * pr[2][o]));
        red[16] = e0 + e1 + e2;
#pragma unroll
        for (int o = 0; o < 17; ++o) {
#pragma unroll
            for (int m = 32; m >= 1; m >>= 1) red[o] += __shfl_xor(red[o], m);
        }
        __syncthreads();
        if (lane == 0) {
#pragma unroll
            for (int o = 0; o < 17; ++o) wred[wid][o] = red[o];
        }
        __syncthreads();
        float sv[17];
#pragma unroll
        for (int o = 0; o < 17; ++o) {
            float tacc = wred[0][o];
#pragma unroll
            for (int w = 1; w < 6; ++w) tacc += wred[w][o];
            sv[o] = tacc;
        }
        float inv = 1.f / sv[16];
        float sn = 0.f;
#pragma unroll
        for (int o = 0; o < 16; ++o) { float s = sv[o] * inv; sn = fmaf(s, s, sn); }
        float scale = (sn / (1.f + sn)) / sqrtf(sn);
#pragma unroll
        for (int o = 0; o < 16; ++o) vout[o] = sv[o] * inv * scale;

        if (it < 2) {
            float d0 = 0.f, d1 = 0.f, d2 = 0.f;
#pragma unroll
            for (int o = 0; o < 16; ++o) {
                d0 = fmaf(pr[0][o], vout[o], d0);
                d1 = fmaf(pr[1][o], vout[o], d1);
                d2 = fmaf(pr[2][o], vout[o], d2);
            }
            l0 += d0; l1 += d1; l2 += d2;
        }
    }
    if (tid < 16) vbuf[(b * 10 + c) * 16 + tid] = vout[tid];
}

// --------------------------------------------------------------------------
// dec1: fused classes/argmax/y_pred + sparse masked GEMM (K=16 of 160).
__global__ __launch_bounds__(512) void dec1_k(const float* __restrict__ vbuf,
                                              const float* __restrict__ dw1,
                                              const float* __restrict__ db1,
                                              float* __restrict__ out,
                                              float* __restrict__ d1) {
    __shared__ float sv[160];
    __shared__ float scls[10];
    __shared__ int sbest;
    int b = blockIdx.x, tid = threadIdx.x;
    if (tid < 160) sv[tid] = vbuf[b * 160 + tid];
    __syncthreads();
    if (tid < 10) {
        float sn = 0.f;
#pragma unroll
        for (int o = 0; o < 16; ++o) { float v = sv[tid * 16 + o]; sn = fmaf(v, v, sn); }
        scls[tid] = sqrtf(sn);
    }
    __syncthreads();
    if (tid == 0) {
        int best = 0; float bv = scls[0];
#pragma unroll
        for (int cc = 1; cc < 10; ++cc) if (scls[cc] > bv) { bv = scls[cc]; best = cc; }
        sbest = best;
    }
    __syncthreads();
    int best = sbest;
    if (tid < 10) {
        out[b * 10 + tid] = (tid == best) ? 1.f : 0.f;          // y_pred
        out[406528 + b * 10 + tid] = scls[tid];                 // classes
    }
    float acc = db1[tid];
    const float* wrow = dw1 + (long)best * 16 * 512;
#pragma unroll
    for (int i = 0; i < 16; ++i)
        acc = fmaf(sv[best * 16 + i], wrow[i * 512 + tid], acc);
    d1[(long)b * 512 + tid] = fmaxf(acc, 0.f);
}

// --------------------------------------------------------------------------
template <int ACT>
__global__ __launch_bounds__(256) void dec_gemm(const float* __restrict__ A,
                                                const float* __restrict__ Bw,
                                                const float* __restrict__ bias,
                                                float* __restrict__ C,
                                                int M, int N, int K) {
    __shared__ float As[16][68];
    __shared__ float Bs[16][68];
    int ntiles = (N + 63) >> 6;
    int mt = blockIdx.x / ntiles, nt = blockIdx.x - mt * ntiles;
    int m0 = mt * 64, n0 = nt * 64;
    int tid = threadIdx.x;
    int tx = tid & 15, ty = tid >> 4;
    int am = tid >> 2, ak = (tid & 3) * 4;
    int bk = tid >> 4, bn = (tid & 15) * 4;
    float acc[4][4];
#pragma unroll
    for (int i = 0; i < 4; ++i)
#pragma unroll
        for (int j = 0; j < 4; ++j) acc[i][j] = 0.f;

    for (int k0 = 0; k0 < K; k0 += 16) {
        float4 av = *(const float4*)(A + (m0 + am) * K + k0 + ak);
        float4 bv = make_float4(0.f, 0.f, 0.f, 0.f);
        if (n0 + bn < N) bv = *(const float4*)(Bw + (k0 + bk) * N + n0 + bn);
        __syncthreads();
        As[ak + 0][am] = av.x;
        As[ak + 1][am] = av.y;
        As[ak + 2][am] = av.z;
        As[ak + 3][am] = av.w;
        *(float4*)&Bs[bk][bn] = bv;
        __syncthreads();
#pragma unroll
        for (int kk = 0; kk < 16; ++kk) {
            float4 a = *(const float4*)&As[kk][ty * 4];
            float4 bb = *(const float4*)&Bs[kk][tx * 4];
            float aa[4] = {a.x, a.y, a.z, a.w};
            float bbb[4] = {bb.x, bb.y, bb.z, bb.w};
#pragma unroll
            for (int i = 0; i < 4; ++i)
#pragma unroll
                for (int j = 0; j < 4; ++j)
                    acc[i][j] = fmaf(aa[i], bbb[j], acc[i][j]);
        }
    }
#pragma unroll
    for (int i = 0; i < 4; ++i) {
        int m = m0 + ty * 4 + i;
#pragma unroll
        for (int j = 0; j < 4; ++j) {
            int n = n0 + tx * 4 + j;
            if (n < N) {
                float v = acc[i][j] + bias[n];
                if (ACT == 0) v = fmaxf(v, 0.f);
                else          v = 1.f / (1.f + expf(-v));
                C[m * N + n] = v;
            }
        }
    }
}

// --------------------------------------------------------------------------
extern "C" void kernel_launch(void* const* d_in, const int* in_sizes, int n_in,
                              void* d_out, int out_size, void* d_ws, size_t ws_size,
                              hipStream_t stream) {
    const float* x   = (const float*)d_in[0];
    const float* w1  = (const float*)d_in[1];
    const float* b1  = (const float*)d_in[2];
    const float* pw  = (const float*)d_in[3];
    const float* pb  = (const float*)d_in[4];
    const float* rw  = (const float*)d_in[5];
    const float* dw1 = (const float*)d_in[6];
    const float* db1 = (const float*)d_in[7];
    const float* dw2 = (const float*)d_in[8];
    const float* db2 = (const float*)d_in[9];
    const float* dw3 = (const float*)d_in[10];
    const float* db3 = (const float*)d_in[11];
    float* out = (float*)d_out;
    char* wsb  = (char*)d_ws;
    if (ws_size < (size_t)WS_BYTES) return;

    h16*   hhi  = (h16*)(wsb + OFFB_HHI);
    h16*   wthi = (h16*)(wsb + OFFB_WTHI);
    h16*   w1t  = (h16*)(wsb + OFFB_WT1);
    float* Cbuf = (float*)(wsb + OFFB_C);
    h16*   pri  = (h16*)(wsb + OFFB_PRI);
    h16*   ut   = (h16*)(wsb + OFFB_UT);
    float* vbuf = (float*)(wsb + OFFB_V);
    float* d1   = (float*)(wsb + OFFB_D1);
    float* d2   = (float*)(wsb + OFFB_D2);

    prep_k<<<18784, 256, 0, stream>>>(w1, pw, w1t, wthi, Cbuf);
    conv1_mfma<<<3200, 256, 0, stream>>>(x, w1t, b1, hhi);
    prim_gemm_mfma<<<2304, 256, 0, stream>>>(hhi, wthi, Cbuf);
    squash_k<<<2304, 256, 0, stream>>>(Cbuf, pb, ut); // h region dead now
    priors_k<<<1440, 256, 0, stream>>>(ut, rw, pri);
    routing2_k<<<5120, 384, 0, stream>>>(pri, vbuf);
    dec1_k<<<512, 512, 0, stream>>>(vbuf, dw1, db1, out, d1);
    dec_gemm<0><<<128, 256, 0, stream>>>(d1, dw2, db2, d2, 512, 1024, 512);
    dec_gemm<1><<<104, 256, 0, stream>>>(d2, dw3, db3, out + 5120, 512, 784, 1024);
}